// Round 5
// baseline (782.240 us; speedup 1.0000x reference)
//
#include <hip/hip_runtime.h>
#include <hip/hip_bf16.h>
#include <cstdint>

#define NV 64000      // B*N nodes
#define DD 64         // hidden dim
#define FF 3          // input features
#define NE 1000000    // edges
#define BB 32         // batch (graphs)
#define SS 50         // timesteps
#define NN 2000       // nodes per graph
#define PCH 16        // pooling chunks per graph
#define KB 1000       // coarse buckets (dst >> 6), 64 dsts each
#define CAP 1536      // records per bucket region (mean 1000, +17 sigma)
#define NBLKA 250     // partition blocks
#define EPB (NE / NBLKA)  // 4000 edges per partition block

// ---------------------------------------------------------------------------
// Detect whether edge_index arrived as int64 (odd int32 words all zero) or
// int32. Branch is wave-uniform in all consumers.
// ---------------------------------------------------------------------------
__global__ void detect_i64_kernel(const int* __restrict__ ei, int* __restrict__ flag) {
    __shared__ int nz;
    int t = threadIdx.x;
    if (t == 0) nz = 0;
    __syncthreads();
    int local = 0;
    for (int i = t; i < 4096; i += blockDim.x)
        local |= (ei[2 * i + 1] != 0);
    if (local) atomicOr(&nz, 1);
    __syncthreads();
    if (t == 0) *flag = (nz == 0) ? 1 : 0;
}

__global__ void zero_aux_kernel(int* __restrict__ gcur) {
    int i = blockIdx.x * blockDim.x + threadIdx.x;
    if (i < KB) gcur[i] = 0;
}

// h0[node*3+f] = mean over S of x[b][s][n][f]
__global__ void tmean_kernel(const float* __restrict__ x, float* __restrict__ h0) {
    int tid = blockIdx.x * blockDim.x + threadIdx.x;  // over NV*FF
    if (tid >= NV * FF) return;
    int nf = tid % (NN * FF);
    int b  = tid / (NN * FF);
    const float* xp = x + (size_t)b * SS * NN * FF + nf;
    float acc = 0.f;
    #pragma unroll
    for (int s = 0; s < SS; ++s) acc += xp[(size_t)s * NN * FF];
    h0[tid] = acc * (1.0f / SS);
}

// ---------------------------------------------------------------------------
// Partition edges into KB coarse bucket regions as packed 4B records
// (src<<6)|(dst&63). Per-block LDS counts -> one global atomic per
// block-bucket -> scatter at global offsets.
// ---------------------------------------------------------------------------
__global__ __launch_bounds__(256) void part_kernel(const int* __restrict__ ei32,
                                                   const int* __restrict__ flag,
                                                   int* __restrict__ gcur,
                                                   unsigned* __restrict__ parts) {
    __shared__ int cnt[KB];
    __shared__ int cur[KB];
    const long long* ei64 = (const long long*)ei32;
    const int is64 = *flag;
    int t = threadIdx.x;
    int e0 = blockIdx.x * EPB;
    for (int i = t; i < KB; i += 256) cnt[i] = 0;
    __syncthreads();
    // pass 1: count valid edges per bucket
    for (int i = t; i < EPB; i += 256) {
        int e = e0 + i;
        int s, d;
        if (is64) { s = (int)ei64[e]; d = (int)ei64[NE + e]; }
        else      { s = ei32[e];      d = ei32[NE + e]; }
        if ((unsigned)s < NV && (unsigned)d < NV) atomicAdd(&cnt[d >> 6], 1);
    }
    __syncthreads();
    // reserve global space per bucket (one atomic per block-bucket)
    for (int b = t; b < KB; b += 256) {
        int c = cnt[b];
        cur[b] = (c > 0) ? atomicAdd(&gcur[b], c) : 0;
    }
    __syncthreads();
    // pass 2: scatter packed records
    for (int i = t; i < EPB; i += 256) {
        int e = e0 + i;
        int s, d;
        if (is64) { s = (int)ei64[e]; d = (int)ei64[NE + e]; }
        else      { s = ei32[e];      d = ei32[NE + e]; }
        if ((unsigned)s < NV && (unsigned)d < NV) {
            int b = d >> 6;
            int pos = atomicAdd(&cur[b], 1);
            if (pos < CAP)
                parts[(size_t)b * CAP + pos] = ((unsigned)s << 6) | (unsigned)(d & 63);
        }
    }
}

// Per-bucket dst histogram -> dinv (with +1 self loop).
__global__ __launch_bounds__(256) void histo_kernel(const unsigned* __restrict__ parts,
                                                    const int* __restrict__ gcur,
                                                    float* __restrict__ dinv) {
    __shared__ int h[64];
    int b = blockIdx.x, t = threadIdx.x;
    if (t < 64) h[t] = 0;
    __syncthreads();
    int cnt = min(gcur[b], CAP);
    const unsigned* p = parts + (size_t)b * CAP;
    for (int i = t; i < cnt; i += 256) atomicAdd(&h[p[i] & 63u], 1);
    __syncthreads();
    if (t < 64) dinv[b * 64 + t] = rsqrtf((float)(h[t] + 1));
}

// g = dinv[node] * (h0 @ W1)
__global__ void transform1_kernel(const float* __restrict__ h0, const float* __restrict__ dinv,
                                  const float* __restrict__ W1, float* __restrict__ gA) {
    int tid = blockIdx.x * blockDim.x + threadIdx.x;  // NV*DD
    if (tid >= NV * DD) return;
    int node = tid >> 6, d = tid & 63;
    float di = dinv[node];
    gA[tid] = di * (h0[node * 3 + 0] * W1[d] +
                    h0[node * 3 + 1] * W1[64 + d] +
                    h0[node * 3 + 2] * W1[128 + d]);
}

// ---------------------------------------------------------------------------
// Bucket aggregation: one block per bucket (64 dst rows in LDS, row-pad 65).
// Init rows with self-loop g[dst]; per record: coalesced 256B gather of
// g[src] + ds_add_f32 into the dst row; one coalesced 16KB writeback.
// ---------------------------------------------------------------------------
__global__ __launch_bounds__(256) void aggb_kernel(const unsigned* __restrict__ parts,
                                                   const int* __restrict__ gcur,
                                                   const float* __restrict__ g,
                                                   float* __restrict__ raw) {
    __shared__ float acc[64 * 65];
    int b = blockIdx.x, t = threadIdx.x;
    int lane = t & 63, wave = t >> 6;
    int node0 = b << 6;
    for (int i = t; i < 64 * 64; i += 256) {
        int row = i >> 6, d = i & 63;
        acc[row * 65 + d] = g[((size_t)(node0 + row) << 6) + d];  // self loop
    }
    __syncthreads();
    int cnt = min(gcur[b], CAP);
    const unsigned* p = parts + (size_t)b * CAP;
    int r = wave;
    for (; r + 12 < cnt; r += 16) {
        unsigned c0 = p[r], c1 = p[r + 4], c2 = p[r + 8], c3 = p[r + 12];
        float v0 = g[((size_t)(c0 >> 6) << 6) + lane];
        float v1 = g[((size_t)(c1 >> 6) << 6) + lane];
        float v2 = g[((size_t)(c2 >> 6) << 6) + lane];
        float v3 = g[((size_t)(c3 >> 6) << 6) + lane];
        atomicAdd(&acc[(c0 & 63u) * 65 + lane], v0);
        atomicAdd(&acc[(c1 & 63u) * 65 + lane], v1);
        atomicAdd(&acc[(c2 & 63u) * 65 + lane], v2);
        atomicAdd(&acc[(c3 & 63u) * 65 + lane], v3);
    }
    for (; r < cnt; r += 4) {
        unsigned c = p[r];
        float v = g[((size_t)(c >> 6) << 6) + lane];
        atomicAdd(&acc[(c & 63u) * 65 + lane], v);
    }
    __syncthreads();
    for (int i = t; i < 64 * 64; i += 256) {
        int row = i >> 6, d = i & 63;
        raw[((size_t)(node0 + row) << 6) + d] = acc[row * 65 + d];
    }
}

// Fused: h1 = relu(dinv*raw1 + b1); g2 = dinv * (h1 @ W2). W2 + 4 rows in LDS.
__global__ __launch_bounds__(256) void transform2_kernel(const float* __restrict__ raw1,
                                                         const float* __restrict__ dinv,
                                                         const float* __restrict__ b1,
                                                         const float* __restrict__ W2,
                                                         float* __restrict__ gA) {
    __shared__ float W2s[64 * 64];
    __shared__ float rows[4 * 64];
    int t = threadIdx.x;
    for (int i = t; i < 64 * 64; i += 256) W2s[i] = W2[i];
    int base = blockIdx.x * 256;
    int node0 = base >> 6;
    {
        int node = node0 + (t >> 6), d = t & 63;
        float v = dinv[node] * raw1[base + t] + b1[d];
        rows[t] = v > 0.f ? v : 0.f;
    }
    __syncthreads();
    int sub = t >> 6, d = t & 63;
    const float* r = &rows[sub * 64];
    float acc = 0.f;
    #pragma unroll 8
    for (int k = 0; k < 64; ++k) acc += r[k] * W2s[k * 64 + d];
    gA[base + t] = dinv[node0 + sub] * acc;
}

// --- Two-phase pooling ---
__global__ __launch_bounds__(256) void pool_part_kernel(const float* __restrict__ rawB,
                                                        const float* __restrict__ dinv,
                                                        const float* __restrict__ b2,
                                                        float* __restrict__ partials) {
    __shared__ float part[4][64];
    int blk = blockIdx.x;
    int b = blk / PCH, c = blk % PCH;
    int t = threadIdx.x;
    int d = t & 63, p = t >> 6;
    const int CHN = NN / PCH;  // 125
    int n0 = b * NN + c * CHN;
    float bias = b2[d];
    float acc = 0.f;
    for (int n = p; n < CHN; n += 4) {
        int node = n0 + n;
        float v = dinv[node] * rawB[((size_t)node << 6) + d] + bias;
        acc += v > 0.f ? v : 0.f;
    }
    part[p][d] = acc;
    __syncthreads();
    if (t < 64) {
        partials[(size_t)blk * 64 + t] =
            part[0][t] + part[1][t] + part[2][t] + part[3][t];
    }
}

__global__ __launch_bounds__(64) void pool_finish_kernel(const float* __restrict__ partials,
                                                         const float* __restrict__ Wh,
                                                         const float* __restrict__ bh,
                                                         float* __restrict__ out) {
    __shared__ float pooled[64];
    int b = blockIdx.x;
    int t = threadIdx.x;
    float s = 0.f;
    #pragma unroll
    for (int c = 0; c < PCH; ++c)
        s += partials[((size_t)b * PCH + c) * 64 + t];
    pooled[t] = s * (1.0f / NN);
    __syncthreads();
    if (t < 2) {
        float o = bh[t];
        #pragma unroll 16
        for (int k = 0; k < 64; ++k) o += pooled[k] * Wh[k * 2 + t];
        out[b * 2 + t] = o;
    }
}

extern "C" void kernel_launch(void* const* d_in, const int* in_sizes, int n_in,
                              void* d_out, int out_size, void* d_ws, size_t ws_size,
                              hipStream_t stream) {
    const float* x  = (const float*)d_in[0];
    const int*   ei = (const int*)d_in[1];
    const float* W1 = (const float*)d_in[2];
    const float* b1 = (const float*)d_in[3];
    const float* W2 = (const float*)d_in[4];
    const float* b2 = (const float*)d_in[5];
    const float* Wh = (const float*)d_in[6];
    const float* bh = (const float*)d_in[7];
    float* out = (float*)d_out;

    float* ws   = (float*)d_ws;
    float* bufA = ws;                          // NV*DD  (g / gather source)
    float* bufB = bufA + (size_t)NV * DD;      // NV*DD  (raw aggregate)
    float* h0   = bufB + (size_t)NV * DD;      // NV*FF
    float* dinv = h0 + (size_t)NV * FF;        // NV
    float* partials = dinv + NV;               // BB*PCH*64
    unsigned* parts = (unsigned*)(partials + BB * PCH * 64);  // KB*CAP
    int*   gcur = (int*)(parts + (size_t)KB * CAP);           // KB
    int*   flag = gcur + KB;                   // 1

    // --- Build bucketed edge partition ---
    detect_i64_kernel<<<1, 256, 0, stream>>>(ei, flag);
    zero_aux_kernel<<<(KB + 255) / 256, 256, 0, stream>>>(gcur);
    tmean_kernel<<<(NV * FF + 255) / 256, 256, 0, stream>>>(x, h0);
    part_kernel<<<NBLKA, 256, 0, stream>>>(ei, flag, gcur, parts);
    histo_kernel<<<KB, 256, 0, stream>>>(parts, gcur, dinv);

    // --- Layer 1 ---
    transform1_kernel<<<NV * DD / 256, 256, 0, stream>>>(h0, dinv, W1, bufA);
    aggb_kernel<<<KB, 256, 0, stream>>>(parts, gcur, bufA, bufB);

    // --- Layer 2 (relu/bias of layer 1 fused into transform) ---
    transform2_kernel<<<NV * DD / 256, 256, 0, stream>>>(bufB, dinv, b1, W2, bufA);
    aggb_kernel<<<KB, 256, 0, stream>>>(parts, gcur, bufA, bufB);

    // --- Pool + head (two-phase) ---
    pool_part_kernel<<<BB * PCH, 256, 0, stream>>>(bufB, dinv, b2, partials);
    pool_finish_kernel<<<BB, 64, 0, stream>>>(partials, Wh, bh, out);
}

// Round 6
// 189.334 us; speedup vs baseline: 4.1315x; 4.1315x over previous
//
#include <hip/hip_runtime.h>
#include <hip/hip_bf16.h>
#include <cstdint>

#define NV 64000      // B*N nodes
#define DD 64         // hidden dim
#define FF 3          // input features
#define NE 1000000    // edges
#define BB 32         // batch (graphs)
#define SS 50         // timesteps
#define NN 2000       // nodes per graph
#define PCH 16        // pooling chunks per graph
#define KB 1000       // coarse buckets (dst >> 6), 64 dsts each
#define CAP 1536      // records per bucket region (mean 1000, +17 sigma)
#define NBLKA 250     // partition blocks
#define EPB (NE / NBLKA)  // 4000 edges per partition block

// ---------------------------------------------------------------------------
// Detect whether edge_index arrived as int64 (odd int32 words all zero) or
// int32. Branch is wave-uniform in all consumers.
// ---------------------------------------------------------------------------
__global__ void detect_i64_kernel(const int* __restrict__ ei, int* __restrict__ flag) {
    __shared__ int nz;
    int t = threadIdx.x;
    if (t == 0) nz = 0;
    __syncthreads();
    int local = 0;
    for (int i = t; i < 4096; i += blockDim.x)
        local |= (ei[2 * i + 1] != 0);
    if (local) atomicOr(&nz, 1);
    __syncthreads();
    if (t == 0) *flag = (nz == 0) ? 1 : 0;
}

__global__ void zero_aux_kernel(int* __restrict__ gcur) {
    int i = blockIdx.x * blockDim.x + threadIdx.x;
    if (i < KB) gcur[i] = 0;
}

// h0[node*3+f] = mean over S of x[b][s][n][f]
__global__ void tmean_kernel(const float* __restrict__ x, float* __restrict__ h0) {
    int tid = blockIdx.x * blockDim.x + threadIdx.x;  // over NV*FF
    if (tid >= NV * FF) return;
    int nf = tid % (NN * FF);
    int b  = tid / (NN * FF);
    const float* xp = x + (size_t)b * SS * NN * FF + nf;
    float acc = 0.f;
    #pragma unroll
    for (int s = 0; s < SS; ++s) acc += xp[(size_t)s * NN * FF];
    h0[tid] = acc * (1.0f / SS);
}

// ---------------------------------------------------------------------------
// Partition edges into KB coarse bucket regions as packed 4B records
// (src<<6)|(dst&63). Per-block LDS counts -> one global atomic per
// block-bucket -> scatter at global offsets.
// ---------------------------------------------------------------------------
__global__ __launch_bounds__(256) void part_kernel(const int* __restrict__ ei32,
                                                   const int* __restrict__ flag,
                                                   int* __restrict__ gcur,
                                                   unsigned* __restrict__ parts) {
    __shared__ int cnt[KB];
    __shared__ int cur[KB];
    const long long* ei64 = (const long long*)ei32;
    const int is64 = *flag;
    int t = threadIdx.x;
    int e0 = blockIdx.x * EPB;
    for (int i = t; i < KB; i += 256) cnt[i] = 0;
    __syncthreads();
    // pass 1: count valid edges per bucket
    for (int i = t; i < EPB; i += 256) {
        int e = e0 + i;
        int s, d;
        if (is64) { s = (int)ei64[e]; d = (int)ei64[NE + e]; }
        else      { s = ei32[e];      d = ei32[NE + e]; }
        if ((unsigned)s < NV && (unsigned)d < NV) atomicAdd(&cnt[d >> 6], 1);
    }
    __syncthreads();
    // reserve global space per bucket (one atomic per block-bucket)
    for (int b = t; b < KB; b += 256) {
        int c = cnt[b];
        cur[b] = (c > 0) ? atomicAdd(&gcur[b], c) : 0;
    }
    __syncthreads();
    // pass 2: scatter packed records
    for (int i = t; i < EPB; i += 256) {
        int e = e0 + i;
        int s, d;
        if (is64) { s = (int)ei64[e]; d = (int)ei64[NE + e]; }
        else      { s = ei32[e];      d = ei32[NE + e]; }
        if ((unsigned)s < NV && (unsigned)d < NV) {
            int b = d >> 6;
            int pos = atomicAdd(&cur[b], 1);
            if (pos < CAP)
                parts[(size_t)b * CAP + pos] = ((unsigned)s << 6) | (unsigned)(d & 63);
        }
    }
}

// ---------------------------------------------------------------------------
// Per-bucket LDS counting sort: histogram(64 dsts) -> dinv; exclusive scan ->
// beg/end (absolute into bucket region); re-scatter; write sorted src ids
// back IN PLACE over the bucket region (block owns it exclusively).
// ---------------------------------------------------------------------------
__global__ __launch_bounds__(256) void bsort_kernel(unsigned* __restrict__ parts,
                                                    const int* __restrict__ gcur,
                                                    int* __restrict__ beg,
                                                    int* __restrict__ end,
                                                    float* __restrict__ dinv) {
    __shared__ unsigned recs[CAP];
    __shared__ int srt[CAP];
    __shared__ int cnt64[64];
    __shared__ int pref[64];
    __shared__ int cur[64];
    int b = blockIdx.x, t = threadIdx.x;
    int cnt = min(gcur[b], CAP);
    unsigned* p = parts + (size_t)b * CAP;
    if (t < 64) cnt64[t] = 0;
    __syncthreads();
    for (int i = t; i < cnt; i += 256) {
        unsigned r = p[i];
        recs[i] = r;
        atomicAdd(&cnt64[r & 63u], 1);
    }
    __syncthreads();
    if (t < 64) pref[t] = cnt64[t];
    __syncthreads();
    #pragma unroll
    for (int off = 1; off < 64; off <<= 1) {
        int v = (t < 64 && t >= off) ? pref[t - off] : 0;
        __syncthreads();
        if (t < 64) pref[t] += v;
        __syncthreads();
    }
    if (t < 64) {
        int ex = pref[t] - cnt64[t];   // exclusive prefix
        cur[t] = ex;
        int node = (b << 6) + t;
        beg[node] = b * CAP + ex;
        end[node] = b * CAP + ex + cnt64[t];
        dinv[node] = rsqrtf((float)(cnt64[t] + 1));  // +1 self loop
    }
    __syncthreads();
    for (int i = t; i < cnt; i += 256) {
        unsigned r = recs[i];
        int pos = atomicAdd(&cur[r & 63u], 1);
        srt[pos] = (int)(r >> 6);
    }
    __syncthreads();
    for (int i = t; i < cnt; i += 256) p[i] = (unsigned)srt[i];
}

// g = dinv[node] * (h0 @ W1)
__global__ void transform1_kernel(const float* __restrict__ h0, const float* __restrict__ dinv,
                                  const float* __restrict__ W1, float* __restrict__ gA) {
    int tid = blockIdx.x * blockDim.x + threadIdx.x;  // NV*DD
    if (tid >= NV * DD) return;
    int node = tid >> 6, d = tid & 63;
    float di = dinv[node];
    gA[tid] = di * (h0[node * 3 + 0] * W1[d] +
                    h0[node * 3 + 1] * W1[64 + d] +
                    h0[node * 3 + 2] * W1[128 + d]);
}

// One wave per dst node: register-accumulate gathered g rows, one 256B store.
// Self loop pre-folded (acc starts at g[node]); dinv[dst] applied downstream.
__global__ __launch_bounds__(256) void agg_kernel(const int* __restrict__ beg,
                                                  const int* __restrict__ end,
                                                  const unsigned* __restrict__ ssorted,
                                                  const float* __restrict__ g,
                                                  float* __restrict__ raw) {
    int lane = threadIdx.x & 63;
    int node = (blockIdx.x * blockDim.x + threadIdx.x) >> 6;
    if (node >= NV) return;
    int e = beg[node], en = end[node];
    float acc = g[((size_t)node << 6) + lane];  // self loop
    for (; e + 4 <= en; e += 4) {
        int s0 = ssorted[e], s1 = ssorted[e + 1], s2 = ssorted[e + 2], s3 = ssorted[e + 3];
        float v0 = g[((size_t)s0 << 6) + lane];
        float v1 = g[((size_t)s1 << 6) + lane];
        float v2 = g[((size_t)s2 << 6) + lane];
        float v3 = g[((size_t)s3 << 6) + lane];
        acc += v0 + v1 + v2 + v3;
    }
    for (; e < en; ++e) acc += g[((size_t)ssorted[e] << 6) + lane];
    raw[((size_t)node << 6) + lane] = acc;
}

// Fused: h1 = relu(dinv*raw1 + b1); g2 = dinv * (h1 @ W2). W2 + 4 rows in LDS.
__global__ __launch_bounds__(256) void transform2_kernel(const float* __restrict__ raw1,
                                                         const float* __restrict__ dinv,
                                                         const float* __restrict__ b1,
                                                         const float* __restrict__ W2,
                                                         float* __restrict__ gA) {
    __shared__ float W2s[64 * 64];
    __shared__ float rows[4 * 64];
    int t = threadIdx.x;
    for (int i = t; i < 64 * 64; i += 256) W2s[i] = W2[i];
    int base = blockIdx.x * 256;
    int node0 = base >> 6;
    {
        int node = node0 + (t >> 6), d = t & 63;
        float v = dinv[node] * raw1[base + t] + b1[d];
        rows[t] = v > 0.f ? v : 0.f;
    }
    __syncthreads();
    int sub = t >> 6, d = t & 63;
    const float* r = &rows[sub * 64];
    float acc = 0.f;
    #pragma unroll 8
    for (int k = 0; k < 64; ++k) acc += r[k] * W2s[k * 64 + d];
    gA[base + t] = dinv[node0 + sub] * acc;
}

// --- Two-phase pooling ---
__global__ __launch_bounds__(256) void pool_part_kernel(const float* __restrict__ rawB,
                                                        const float* __restrict__ dinv,
                                                        const float* __restrict__ b2,
                                                        float* __restrict__ partials) {
    __shared__ float part[4][64];
    int blk = blockIdx.x;
    int b = blk / PCH, c = blk % PCH;
    int t = threadIdx.x;
    int d = t & 63, p = t >> 6;
    const int CHN = NN / PCH;  // 125
    int n0 = b * NN + c * CHN;
    float bias = b2[d];
    float acc = 0.f;
    for (int n = p; n < CHN; n += 4) {
        int node = n0 + n;
        float v = dinv[node] * rawB[((size_t)node << 6) + d] + bias;
        acc += v > 0.f ? v : 0.f;
    }
    part[p][d] = acc;
    __syncthreads();
    if (t < 64) {
        partials[(size_t)blk * 64 + t] =
            part[0][t] + part[1][t] + part[2][t] + part[3][t];
    }
}

__global__ __launch_bounds__(64) void pool_finish_kernel(const float* __restrict__ partials,
                                                         const float* __restrict__ Wh,
                                                         const float* __restrict__ bh,
                                                         float* __restrict__ out) {
    __shared__ float pooled[64];
    int b = blockIdx.x;
    int t = threadIdx.x;
    float s = 0.f;
    #pragma unroll
    for (int c = 0; c < PCH; ++c)
        s += partials[((size_t)b * PCH + c) * 64 + t];
    pooled[t] = s * (1.0f / NN);
    __syncthreads();
    if (t < 2) {
        float o = bh[t];
        #pragma unroll 16
        for (int k = 0; k < 64; ++k) o += pooled[k] * Wh[k * 2 + t];
        out[b * 2 + t] = o;
    }
}

extern "C" void kernel_launch(void* const* d_in, const int* in_sizes, int n_in,
                              void* d_out, int out_size, void* d_ws, size_t ws_size,
                              hipStream_t stream) {
    const float* x  = (const float*)d_in[0];
    const int*   ei = (const int*)d_in[1];
    const float* W1 = (const float*)d_in[2];
    const float* b1 = (const float*)d_in[3];
    const float* W2 = (const float*)d_in[4];
    const float* b2 = (const float*)d_in[5];
    const float* Wh = (const float*)d_in[6];
    const float* bh = (const float*)d_in[7];
    float* out = (float*)d_out;

    float* ws   = (float*)d_ws;
    float* bufA = ws;                          // NV*DD  (g / gather source)
    float* bufB = bufA + (size_t)NV * DD;      // NV*DD  (raw aggregate)
    float* h0   = bufB + (size_t)NV * DD;      // NV*FF
    float* dinv = h0 + (size_t)NV * FF;        // NV
    float* partials = dinv + NV;               // BB*PCH*64
    unsigned* parts = (unsigned*)(partials + BB * PCH * 64);  // KB*CAP (records -> sorted srcs)
    int*   beg  = (int*)(parts + (size_t)KB * CAP);           // NV
    int*   end  = beg + NV;                    // NV
    int*   gcur = end + NV;                    // KB
    int*   flag = gcur + KB;                   // 1

    // --- Build bucketed, per-bucket-sorted edge structure ---
    detect_i64_kernel<<<1, 256, 0, stream>>>(ei, flag);
    zero_aux_kernel<<<(KB + 255) / 256, 256, 0, stream>>>(gcur);
    tmean_kernel<<<(NV * FF + 255) / 256, 256, 0, stream>>>(x, h0);
    part_kernel<<<NBLKA, 256, 0, stream>>>(ei, flag, gcur, parts);
    bsort_kernel<<<KB, 256, 0, stream>>>(parts, gcur, beg, end, dinv);

    // --- Layer 1 ---
    transform1_kernel<<<NV * DD / 256, 256, 0, stream>>>(h0, dinv, W1, bufA);
    agg_kernel<<<NV * 64 / 256, 256, 0, stream>>>(beg, end, parts, bufA, bufB);

    // --- Layer 2 (relu/bias of layer 1 fused into transform) ---
    transform2_kernel<<<NV * DD / 256, 256, 0, stream>>>(bufB, dinv, b1, W2, bufA);
    agg_kernel<<<NV * 64 / 256, 256, 0, stream>>>(beg, end, parts, bufA, bufB);

    // --- Pool + head (two-phase) ---
    pool_part_kernel<<<BB * PCH, 256, 0, stream>>>(bufB, dinv, b2, partials);
    pool_finish_kernel<<<BB, 64, 0, stream>>>(partials, Wh, bh, out);
}

// Round 7
// 157.913 us; speedup vs baseline: 4.9536x; 1.1990x over previous
//
#include <hip/hip_runtime.h>
#include <hip/hip_bf16.h>
#include <cstdint>

#define NV 64000      // B*N nodes
#define DD 64         // hidden dim
#define FF 3          // input features
#define NE 1000000    // edges
#define BB 32         // batch (graphs)
#define SS 50         // timesteps
#define NN 2000       // nodes per graph
#define PCH 16        // pooling chunks per graph
#define KB 1000       // coarse buckets (dst >> 6), 64 dsts each
#define CAP 1536      // records per bucket region (mean 1000, +17 sigma)
#define NBLKA 250     // partition blocks
#define EPB (NE / NBLKA)  // 4000 edges per partition block

// ---------------------------------------------------------------------------
// Detect whether edge_index arrived as int64 (odd int32 words all zero) or
// int32. Branch is wave-uniform in all consumers.
// ---------------------------------------------------------------------------
__global__ void detect_i64_kernel(const int* __restrict__ ei, int* __restrict__ flag) {
    __shared__ int nz;
    int t = threadIdx.x;
    if (t == 0) nz = 0;
    __syncthreads();
    int local = 0;
    for (int i = t; i < 4096; i += blockDim.x)
        local |= (ei[2 * i + 1] != 0);
    if (local) atomicOr(&nz, 1);
    __syncthreads();
    if (t == 0) *flag = (nz == 0) ? 1 : 0;
}

__global__ void zero_aux_kernel(int* __restrict__ gcur) {
    int i = blockIdx.x * blockDim.x + threadIdx.x;
    if (i < KB) gcur[i] = 0;
}

// ---------------------------------------------------------------------------
// Partition edges into KB coarse bucket regions as packed 4B records
// (src<<6)|(dst&63). Per-block LDS counts -> one global atomic per
// block-bucket -> scatter at global offsets.
// ---------------------------------------------------------------------------
__global__ __launch_bounds__(256) void part_kernel(const int* __restrict__ ei32,
                                                   const int* __restrict__ flag,
                                                   int* __restrict__ gcur,
                                                   unsigned* __restrict__ parts) {
    __shared__ int cnt[KB];
    __shared__ int cur[KB];
    const long long* ei64 = (const long long*)ei32;
    const int is64 = *flag;
    int t = threadIdx.x;
    int e0 = blockIdx.x * EPB;
    for (int i = t; i < KB; i += 256) cnt[i] = 0;
    __syncthreads();
    // pass 1: count valid edges per bucket
    for (int i = t; i < EPB; i += 256) {
        int e = e0 + i;
        int s, d;
        if (is64) { s = (int)ei64[e]; d = (int)ei64[NE + e]; }
        else      { s = ei32[e];      d = ei32[NE + e]; }
        if ((unsigned)s < NV && (unsigned)d < NV) atomicAdd(&cnt[d >> 6], 1);
    }
    __syncthreads();
    // reserve global space per bucket (one atomic per block-bucket)
    for (int b = t; b < KB; b += 256) {
        int c = cnt[b];
        cur[b] = (c > 0) ? atomicAdd(&gcur[b], c) : 0;
    }
    __syncthreads();
    // pass 2: scatter packed records
    for (int i = t; i < EPB; i += 256) {
        int e = e0 + i;
        int s, d;
        if (is64) { s = (int)ei64[e]; d = (int)ei64[NE + e]; }
        else      { s = ei32[e];      d = ei32[NE + e]; }
        if ((unsigned)s < NV && (unsigned)d < NV) {
            int b = d >> 6;
            int pos = atomicAdd(&cur[b], 1);
            if (pos < CAP)
                parts[(size_t)b * CAP + pos] = ((unsigned)s << 6) | (unsigned)(d & 63);
        }
    }
}

// ---------------------------------------------------------------------------
// Per-bucket LDS counting sort: histogram(64 dsts) -> dinv; exclusive scan ->
// beg/end (absolute into bucket region); re-scatter; write sorted src ids
// back IN PLACE over the bucket region (block owns it exclusively).
// ---------------------------------------------------------------------------
__global__ __launch_bounds__(256) void bsort_kernel(unsigned* __restrict__ parts,
                                                    const int* __restrict__ gcur,
                                                    int* __restrict__ beg,
                                                    int* __restrict__ end,
                                                    float* __restrict__ dinv) {
    __shared__ unsigned recs[CAP];
    __shared__ int srt[CAP];
    __shared__ int cnt64[64];
    __shared__ int pref[64];
    __shared__ int cur[64];
    int b = blockIdx.x, t = threadIdx.x;
    int cnt = min(gcur[b], CAP);
    unsigned* p = parts + (size_t)b * CAP;
    if (t < 64) cnt64[t] = 0;
    __syncthreads();
    for (int i = t; i < cnt; i += 256) {
        unsigned r = p[i];
        recs[i] = r;
        atomicAdd(&cnt64[r & 63u], 1);
    }
    __syncthreads();
    if (t < 64) pref[t] = cnt64[t];
    __syncthreads();
    #pragma unroll
    for (int off = 1; off < 64; off <<= 1) {
        int v = (t < 64 && t >= off) ? pref[t - off] : 0;
        __syncthreads();
        if (t < 64) pref[t] += v;
        __syncthreads();
    }
    if (t < 64) {
        int ex = pref[t] - cnt64[t];   // exclusive prefix
        cur[t] = ex;
        int node = (b << 6) + t;
        beg[node] = b * CAP + ex;
        end[node] = b * CAP + ex + cnt64[t];
        dinv[node] = rsqrtf((float)(cnt64[t] + 1));  // +1 self loop
    }
    __syncthreads();
    for (int i = t; i < cnt; i += 256) {
        unsigned r = recs[i];
        int pos = atomicAdd(&cur[r & 63u], 1);
        srt[pos] = (int)(r >> 6);
    }
    __syncthreads();
    for (int i = t; i < cnt; i += 256) p[i] = (unsigned)srt[i];
}

// p0[node*3+f] = dinv[node] * mean over S of x[b][s][n][f]
__global__ void tmean_kernel(const float* __restrict__ x, const float* __restrict__ dinv,
                             float* __restrict__ p0) {
    int tid = blockIdx.x * blockDim.x + threadIdx.x;  // over NV*FF
    if (tid >= NV * FF) return;
    int nf = tid % (NN * FF);
    int b  = tid / (NN * FF);
    const float* xp = x + (size_t)b * SS * NN * FF + nf;
    float acc = 0.f;
    #pragma unroll
    for (int s = 0; s < SS; ++s) acc += xp[(size_t)s * NN * FF];
    int node = tid / 3;
    p0[tid] = dinv[node] * acc * (1.0f / SS);
}

// 3-dim aggregation: one thread per dst node. q0 = sum p0[src] + p0[dst].
// p0 is 768 KB -> resident in every XCD L2; gather is nearly free.
__global__ __launch_bounds__(256) void agg3_kernel(const int* __restrict__ beg,
                                                   const int* __restrict__ end,
                                                   const unsigned* __restrict__ srcs,
                                                   const float* __restrict__ p0,
                                                   float* __restrict__ q0) {
    int node = blockIdx.x * 256 + threadIdx.x;
    if (node >= NV) return;
    int e = beg[node], en = end[node];
    float a0 = p0[node * 3 + 0], a1 = p0[node * 3 + 1], a2 = p0[node * 3 + 2];
    for (; e + 2 <= en; e += 2) {
        int s0 = srcs[e] * 3, s1 = srcs[e + 1] * 3;
        float u0 = p0[s0], u1 = p0[s0 + 1], u2 = p0[s0 + 2];
        float w0 = p0[s1], w1 = p0[s1 + 1], w2 = p0[s1 + 2];
        a0 += u0 + w0; a1 += u1 + w1; a2 += u2 + w2;
    }
    for (; e < en; ++e) {
        int s = srcs[e] * 3;
        a0 += p0[s]; a1 += p0[s + 1]; a2 += p0[s + 2];
    }
    q0[node * 3 + 0] = a0;
    q0[node * 3 + 1] = a1;
    q0[node * 3 + 2] = a2;
}

// h1 = relu(dinv*(q0@W1) + b1); p1 = dinv*h1 (ready for layer-2 aggregation).
__global__ void trans1_kernel(const float* __restrict__ q0, const float* __restrict__ dinv,
                              const float* __restrict__ W1, const float* __restrict__ b1,
                              float* __restrict__ p1) {
    int tid = blockIdx.x * blockDim.x + threadIdx.x;  // NV*DD
    if (tid >= NV * DD) return;
    int node = tid >> 6, d = tid & 63;
    float di = dinv[node];
    float h = di * (q0[node * 3 + 0] * W1[d] +
                    q0[node * 3 + 1] * W1[64 + d] +
                    q0[node * 3 + 2] * W1[128 + d]) + b1[d];
    h = h > 0.f ? h : 0.f;
    p1[tid] = di * h;
}

// One wave per dst node: register-accumulate gathered p1 rows, one 256B store.
// Self loop pre-folded (acc starts at p1[node]).
__global__ __launch_bounds__(256) void agg64_kernel(const int* __restrict__ beg,
                                                    const int* __restrict__ end,
                                                    const unsigned* __restrict__ ssorted,
                                                    const float* __restrict__ g,
                                                    float* __restrict__ raw) {
    int lane = threadIdx.x & 63;
    int node = (blockIdx.x * blockDim.x + threadIdx.x) >> 6;
    if (node >= NV) return;
    int e = beg[node], en = end[node];
    float acc = g[((size_t)node << 6) + lane];  // self loop
    for (; e + 8 <= en; e += 8) {
        int s0 = ssorted[e], s1 = ssorted[e + 1], s2 = ssorted[e + 2], s3 = ssorted[e + 3];
        int s4 = ssorted[e + 4], s5 = ssorted[e + 5], s6 = ssorted[e + 6], s7 = ssorted[e + 7];
        float v0 = g[((size_t)s0 << 6) + lane];
        float v1 = g[((size_t)s1 << 6) + lane];
        float v2 = g[((size_t)s2 << 6) + lane];
        float v3 = g[((size_t)s3 << 6) + lane];
        float v4 = g[((size_t)s4 << 6) + lane];
        float v5 = g[((size_t)s5 << 6) + lane];
        float v6 = g[((size_t)s6 << 6) + lane];
        float v7 = g[((size_t)s7 << 6) + lane];
        acc += ((v0 + v1) + (v2 + v3)) + ((v4 + v5) + (v6 + v7));
    }
    for (; e < en; ++e) acc += g[((size_t)ssorted[e] << 6) + lane];
    raw[((size_t)node << 6) + lane] = acc;
}

// h2 = relu(dinv*(q1@W2) + b2). W2 + 4 q1-rows staged in LDS.
__global__ __launch_bounds__(256) void trans2_kernel(const float* __restrict__ q1,
                                                     const float* __restrict__ dinv,
                                                     const float* __restrict__ b2,
                                                     const float* __restrict__ W2,
                                                     float* __restrict__ h2) {
    __shared__ float W2s[64 * 64];
    __shared__ float rows[4 * 64];
    int t = threadIdx.x;
    for (int i = t; i < 64 * 64; i += 256) W2s[i] = W2[i];
    int base = blockIdx.x * 256;
    int node0 = base >> 6;
    rows[t] = q1[base + t];
    __syncthreads();
    int sub = t >> 6, d = t & 63;
    const float* r = &rows[sub * 64];
    float acc = 0.f;
    #pragma unroll 8
    for (int k = 0; k < 64; ++k) acc += r[k] * W2s[k * 64 + d];
    float v = dinv[node0 + sub] * acc + b2[d];
    h2[base + t] = v > 0.f ? v : 0.f;
}

// --- Two-phase pooling (h2 already relu'd) ---
__global__ __launch_bounds__(256) void pool_part_kernel(const float* __restrict__ h2,
                                                        float* __restrict__ partials) {
    __shared__ float part[4][64];
    int blk = blockIdx.x;
    int b = blk / PCH, c = blk % PCH;
    int t = threadIdx.x;
    int d = t & 63, p = t >> 6;
    const int CHN = NN / PCH;  // 125
    int n0 = b * NN + c * CHN;
    float acc = 0.f;
    for (int n = p; n < CHN; n += 4)
        acc += h2[((size_t)(n0 + n) << 6) + d];
    part[p][d] = acc;
    __syncthreads();
    if (t < 64) {
        partials[(size_t)blk * 64 + t] =
            part[0][t] + part[1][t] + part[2][t] + part[3][t];
    }
}

__global__ __launch_bounds__(64) void pool_finish_kernel(const float* __restrict__ partials,
                                                         const float* __restrict__ Wh,
                                                         const float* __restrict__ bh,
                                                         float* __restrict__ out) {
    __shared__ float pooled[64];
    int b = blockIdx.x;
    int t = threadIdx.x;
    float s = 0.f;
    #pragma unroll
    for (int c = 0; c < PCH; ++c)
        s += partials[((size_t)b * PCH + c) * 64 + t];
    pooled[t] = s * (1.0f / NN);
    __syncthreads();
    if (t < 2) {
        float o = bh[t];
        #pragma unroll 16
        for (int k = 0; k < 64; ++k) o += pooled[k] * Wh[k * 2 + t];
        out[b * 2 + t] = o;
    }
}

extern "C" void kernel_launch(void* const* d_in, const int* in_sizes, int n_in,
                              void* d_out, int out_size, void* d_ws, size_t ws_size,
                              hipStream_t stream) {
    const float* x  = (const float*)d_in[0];
    const int*   ei = (const int*)d_in[1];
    const float* W1 = (const float*)d_in[2];
    const float* b1 = (const float*)d_in[3];
    const float* W2 = (const float*)d_in[4];
    const float* b2 = (const float*)d_in[5];
    const float* Wh = (const float*)d_in[6];
    const float* bh = (const float*)d_in[7];
    float* out = (float*)d_out;

    float* ws   = (float*)d_ws;
    float* bufA = ws;                          // NV*DD  (p1, then h2)
    float* bufB = bufA + (size_t)NV * DD;      // NV*DD  (q1)
    float* p0   = bufB + (size_t)NV * DD;      // NV*FF
    float* q0   = p0 + (size_t)NV * FF;        // NV*FF
    float* dinv = q0 + (size_t)NV * FF;        // NV
    float* partials = dinv + NV;               // BB*PCH*64
    unsigned* parts = (unsigned*)(partials + BB * PCH * 64);  // KB*CAP
    int*   beg  = (int*)(parts + (size_t)KB * CAP);           // NV
    int*   end  = beg + NV;                    // NV
    int*   gcur = end + NV;                    // KB
    int*   flag = gcur + KB;                   // 1

    // --- Build bucketed, per-bucket-sorted edge structure ---
    detect_i64_kernel<<<1, 256, 0, stream>>>(ei, flag);
    zero_aux_kernel<<<(KB + 255) / 256, 256, 0, stream>>>(gcur);
    part_kernel<<<NBLKA, 256, 0, stream>>>(ei, flag, gcur, parts);
    bsort_kernel<<<KB, 256, 0, stream>>>(parts, gcur, beg, end, dinv);

    // --- p0 = dinv * temporal-mean(x) ---
    tmean_kernel<<<(NV * FF + 255) / 256, 256, 0, stream>>>(x, dinv, p0);

    // --- Layer 1 (aggregate-then-transform, 3-dim gather) ---
    agg3_kernel<<<(NV + 255) / 256, 256, 0, stream>>>(beg, end, parts, p0, q0);
    trans1_kernel<<<NV * DD / 256, 256, 0, stream>>>(q0, dinv, W1, b1, bufA);

    // --- Layer 2 (aggregate-then-transform, 64-dim gather) ---
    agg64_kernel<<<NV * 64 / 256, 256, 0, stream>>>(beg, end, parts, bufA, bufB);
    trans2_kernel<<<NV * DD / 256, 256, 0, stream>>>(bufB, dinv, b2, W2, bufA);

    // --- Pool + head (two-phase) ---
    pool_part_kernel<<<BB * PCH, 256, 0, stream>>>(bufA, partials);
    pool_finish_kernel<<<BB, 64, 0, stream>>>(partials, Wh, bh, out);
}

// Round 8
// 145.656 us; speedup vs baseline: 5.3705x; 1.0841x over previous
//
#include <hip/hip_runtime.h>
#include <hip/hip_bf16.h>
#include <cstdint>

#define NV 64000      // B*N nodes
#define DD 64         // hidden dim
#define FF 3          // input features
#define NE 1000000    // edges
#define BB 32         // batch (graphs)
#define SS 50         // timesteps
#define NN 2000       // nodes per graph
#define PCH 16        // pooling chunks per graph
#define KB 1000       // coarse buckets (dst >> 6), 64 dsts each
#define CAP 1536      // records per bucket region (mean 1000, +17 sigma)
#define NBLKA 250     // partition blocks
#define EPB (NE / NBLKA)  // 4000 edges per partition block
#define INVALID 0xFFFFFFFFu

// ---------------------------------------------------------------------------
// Fused setup: zero gcur (4 blocks x 256 >= KB) + int64-vs-int32 detection
// (block 0: odd int32 words of int64 indices < 2^31 are all zero).
// ---------------------------------------------------------------------------
__global__ __launch_bounds__(256) void setup_kernel(const int* __restrict__ ei,
                                                    int* __restrict__ flag,
                                                    int* __restrict__ gcur) {
    int i = blockIdx.x * 256 + threadIdx.x;
    if (i < KB) gcur[i] = 0;
    if (blockIdx.x == 0) {
        __shared__ int nz;
        if (threadIdx.x == 0) nz = 0;
        __syncthreads();
        int local = 0;
        for (int k = threadIdx.x; k < 4096; k += 256)
            local |= (ei[2 * k + 1] != 0);
        if (local) atomicOr(&nz, 1);
        __syncthreads();
        if (threadIdx.x == 0) *flag = (nz == 0) ? 1 : 0;
    }
}

// ---------------------------------------------------------------------------
// Partition edges into KB coarse bucket regions as packed 4B records
// (src<<6)|(dst&63). Single edge-list read: records staged in LDS
// (validity-marked slots), per-block LDS counts -> one global atomic per
// block-bucket -> scatter from LDS at global offsets.
// ---------------------------------------------------------------------------
__global__ __launch_bounds__(256) void part_kernel(const int* __restrict__ ei32,
                                                   const int* __restrict__ flag,
                                                   int* __restrict__ gcur,
                                                   unsigned* __restrict__ parts) {
    __shared__ unsigned recs[EPB];   // 16 KB: (s<<16)|d or INVALID
    __shared__ int cnt[KB];          // 4 KB
    __shared__ int cur[KB];          // 4 KB
    const long long* ei64 = (const long long*)ei32;
    const int is64 = *flag;
    int t = threadIdx.x;
    int e0 = blockIdx.x * EPB;
    for (int i = t; i < KB; i += 256) cnt[i] = 0;
    __syncthreads();
    // pass 1: load edges once, stage packed records, count per bucket
    for (int i = t; i < EPB; i += 256) {
        int e = e0 + i;
        int s, d;
        if (is64) { s = (int)ei64[e]; d = (int)ei64[NE + e]; }
        else      { s = ei32[e];      d = ei32[NE + e]; }
        bool ok = (unsigned)s < NV && (unsigned)d < NV;
        recs[i] = ok ? (((unsigned)s << 16) | (unsigned)d) : INVALID;
        if (ok) atomicAdd(&cnt[d >> 6], 1);
    }
    __syncthreads();
    // reserve global space per bucket (one atomic per block-bucket)
    for (int b = t; b < KB; b += 256) {
        int c = cnt[b];
        cur[b] = (c > 0) ? atomicAdd(&gcur[b], c) : 0;
    }
    __syncthreads();
    // pass 2: scatter from LDS
    for (int i = t; i < EPB; i += 256) {
        unsigned r = recs[i];
        if (r != INVALID) {
            int d = (int)(r & 0xFFFFu);
            int b = d >> 6;
            int pos = atomicAdd(&cur[b], 1);
            if (pos < CAP)
                parts[(size_t)b * CAP + pos] = ((r >> 16) << 6) | (unsigned)(d & 63);
        }
    }
}

// ---------------------------------------------------------------------------
// Per-bucket LDS counting sort: histogram(64 dsts) -> dinv; exclusive scan ->
// beg/end (absolute into bucket region); re-scatter; write sorted src ids
// back IN PLACE over the bucket region (block owns it exclusively).
// ---------------------------------------------------------------------------
__global__ __launch_bounds__(256) void bsort_kernel(unsigned* __restrict__ parts,
                                                    const int* __restrict__ gcur,
                                                    int* __restrict__ beg,
                                                    int* __restrict__ end,
                                                    float* __restrict__ dinv) {
    __shared__ unsigned recs[CAP];
    __shared__ int srt[CAP];
    __shared__ int cnt64[64];
    __shared__ int pref[64];
    __shared__ int cur[64];
    int b = blockIdx.x, t = threadIdx.x;
    int cnt = min(gcur[b], CAP);
    unsigned* p = parts + (size_t)b * CAP;
    if (t < 64) cnt64[t] = 0;
    __syncthreads();
    for (int i = t; i < cnt; i += 256) {
        unsigned r = p[i];
        recs[i] = r;
        atomicAdd(&cnt64[r & 63u], 1);
    }
    __syncthreads();
    if (t < 64) pref[t] = cnt64[t];
    __syncthreads();
    #pragma unroll
    for (int off = 1; off < 64; off <<= 1) {
        int v = (t < 64 && t >= off) ? pref[t - off] : 0;
        __syncthreads();
        if (t < 64) pref[t] += v;
        __syncthreads();
    }
    if (t < 64) {
        int ex = pref[t] - cnt64[t];   // exclusive prefix
        cur[t] = ex;
        int node = (b << 6) + t;
        beg[node] = b * CAP + ex;
        end[node] = b * CAP + ex + cnt64[t];
        dinv[node] = rsqrtf((float)(cnt64[t] + 1));  // +1 self loop
    }
    __syncthreads();
    for (int i = t; i < cnt; i += 256) {
        unsigned r = recs[i];
        int pos = atomicAdd(&cur[r & 63u], 1);
        srt[pos] = (int)(r >> 6);
    }
    __syncthreads();
    for (int i = t; i < cnt; i += 256) p[i] = (unsigned)srt[i];
}

// p0[node*3+f] = dinv[node] * mean over S of x[b][s][n][f]
__global__ void tmean_kernel(const float* __restrict__ x, const float* __restrict__ dinv,
                             float* __restrict__ p0) {
    int tid = blockIdx.x * blockDim.x + threadIdx.x;  // over NV*FF
    if (tid >= NV * FF) return;
    int nf = tid % (NN * FF);
    int b  = tid / (NN * FF);
    const float* xp = x + (size_t)b * SS * NN * FF + nf;
    float acc = 0.f;
    #pragma unroll
    for (int s = 0; s < SS; ++s) acc += xp[(size_t)s * NN * FF];
    int node = tid / 3;
    p0[tid] = dinv[node] * acc * (1.0f / SS);
}

// 3-dim aggregation: one thread per dst node. q04 = {sum p0[src] + p0[dst], dinv}.
// p0 is 768 KB -> resident in every XCD L2; gather is nearly free.
__global__ __launch_bounds__(256) void agg3_kernel(const int* __restrict__ beg,
                                                   const int* __restrict__ end,
                                                   const unsigned* __restrict__ srcs,
                                                   const float* __restrict__ p0,
                                                   const float* __restrict__ dinv,
                                                   float4* __restrict__ q04) {
    int node = blockIdx.x * 256 + threadIdx.x;
    if (node >= NV) return;
    int e = beg[node], en = end[node];
    float a0 = p0[node * 3 + 0], a1 = p0[node * 3 + 1], a2 = p0[node * 3 + 2];
    for (; e + 2 <= en; e += 2) {
        int s0 = srcs[e] * 3, s1 = srcs[e + 1] * 3;
        float u0 = p0[s0], u1 = p0[s0 + 1], u2 = p0[s0 + 2];
        float w0 = p0[s1], w1 = p0[s1 + 1], w2 = p0[s1 + 2];
        a0 += u0 + w0; a1 += u1 + w1; a2 += u2 + w2;
    }
    for (; e < en; ++e) {
        int s = srcs[e] * 3;
        a0 += p0[s]; a1 += p0[s + 1]; a2 += p0[s + 2];
    }
    q04[node] = make_float4(a0, a1, a2, dinv[node]);
}

// ---------------------------------------------------------------------------
// Fused layer-1 transform + layer-2 aggregation. One wave per dst node.
// p1[s][lane] = dinv[s]*relu(dinv[s]*(q0[s]@W1[:,lane]) + b1[lane]) computed
// on the fly from a 16B gather of q04[s] (1 MB buffer, L2-resident on every
// XCD). W1 columns + b1 held in registers. One 256B store of q1[dst].
// ---------------------------------------------------------------------------
__global__ __launch_bounds__(256) void aggf_kernel(const int* __restrict__ beg,
                                                   const int* __restrict__ end,
                                                   const unsigned* __restrict__ srcs,
                                                   const float4* __restrict__ q04,
                                                   const float* __restrict__ W1,
                                                   const float* __restrict__ b1,
                                                   float* __restrict__ q1) {
    int lane = threadIdx.x & 63;
    int node = (blockIdx.x * blockDim.x + threadIdx.x) >> 6;
    if (node >= NV) return;
    float w0 = W1[lane], w1 = W1[64 + lane], w2 = W1[128 + lane], bb = b1[lane];
    int e = beg[node], en = end[node];
    float4 qn = q04[node];  // self loop
    float h = fmaf(qn.w, fmaf(qn.x, w0, fmaf(qn.y, w1, qn.z * w2)), bb);
    float acc = qn.w * fmaxf(h, 0.f);
    for (; e + 4 <= en; e += 4) {
        float4 a = q04[srcs[e]];
        float4 b = q04[srcs[e + 1]];
        float4 c = q04[srcs[e + 2]];
        float4 d = q04[srcs[e + 3]];
        float ha = fmaf(a.w, fmaf(a.x, w0, fmaf(a.y, w1, a.z * w2)), bb);
        float hb = fmaf(b.w, fmaf(b.x, w0, fmaf(b.y, w1, b.z * w2)), bb);
        float hc = fmaf(c.w, fmaf(c.x, w0, fmaf(c.y, w1, c.z * w2)), bb);
        float hd = fmaf(d.w, fmaf(d.x, w0, fmaf(d.y, w1, d.z * w2)), bb);
        acc += a.w * fmaxf(ha, 0.f) + b.w * fmaxf(hb, 0.f)
             + c.w * fmaxf(hc, 0.f) + d.w * fmaxf(hd, 0.f);
    }
    for (; e < en; ++e) {
        float4 a = q04[srcs[e]];
        float ha = fmaf(a.w, fmaf(a.x, w0, fmaf(a.y, w1, a.z * w2)), bb);
        acc += a.w * fmaxf(ha, 0.f);
    }
    q1[((size_t)node << 6) + lane] = acc;
}

// h2 = relu(dinv*(q1@W2) + b2). W2 + 4 q1-rows staged in LDS.
__global__ __launch_bounds__(256) void trans2_kernel(const float* __restrict__ q1,
                                                     const float* __restrict__ dinv,
                                                     const float* __restrict__ b2,
                                                     const float* __restrict__ W2,
                                                     float* __restrict__ h2) {
    __shared__ float W2s[64 * 64];
    __shared__ float rows[4 * 64];
    int t = threadIdx.x;
    for (int i = t; i < 64 * 64; i += 256) W2s[i] = W2[i];
    int base = blockIdx.x * 256;
    int node0 = base >> 6;
    rows[t] = q1[base + t];
    __syncthreads();
    int sub = t >> 6, d = t & 63;
    const float* r = &rows[sub * 64];
    float acc = 0.f;
    #pragma unroll 8
    for (int k = 0; k < 64; ++k) acc += r[k] * W2s[k * 64 + d];
    float v = dinv[node0 + sub] * acc + b2[d];
    h2[base + t] = v > 0.f ? v : 0.f;
}

// --- Two-phase pooling (h2 already relu'd) ---
__global__ __launch_bounds__(256) void pool_part_kernel(const float* __restrict__ h2,
                                                        float* __restrict__ partials) {
    __shared__ float part[4][64];
    int blk = blockIdx.x;
    int b = blk / PCH, c = blk % PCH;
    int t = threadIdx.x;
    int d = t & 63, p = t >> 6;
    const int CHN = NN / PCH;  // 125
    int n0 = b * NN + c * CHN;
    float acc = 0.f;
    for (int n = p; n < CHN; n += 4)
        acc += h2[((size_t)(n0 + n) << 6) + d];
    part[p][d] = acc;
    __syncthreads();
    if (t < 64) {
        partials[(size_t)blk * 64 + t] =
            part[0][t] + part[1][t] + part[2][t] + part[3][t];
    }
}

__global__ __launch_bounds__(64) void pool_finish_kernel(const float* __restrict__ partials,
                                                         const float* __restrict__ Wh,
                                                         const float* __restrict__ bh,
                                                         float* __restrict__ out) {
    __shared__ float pooled[64];
    int b = blockIdx.x;
    int t = threadIdx.x;
    float s = 0.f;
    #pragma unroll
    for (int c = 0; c < PCH; ++c)
        s += partials[((size_t)b * PCH + c) * 64 + t];
    pooled[t] = s * (1.0f / NN);
    __syncthreads();
    if (t < 2) {
        float o = bh[t];
        #pragma unroll 16
        for (int k = 0; k < 64; ++k) o += pooled[k] * Wh[k * 2 + t];
        out[b * 2 + t] = o;
    }
}

extern "C" void kernel_launch(void* const* d_in, const int* in_sizes, int n_in,
                              void* d_out, int out_size, void* d_ws, size_t ws_size,
                              hipStream_t stream) {
    const float* x  = (const float*)d_in[0];
    const int*   ei = (const int*)d_in[1];
    const float* W1 = (const float*)d_in[2];
    const float* b1 = (const float*)d_in[3];
    const float* W2 = (const float*)d_in[4];
    const float* b2 = (const float*)d_in[5];
    const float* Wh = (const float*)d_in[6];
    const float* bh = (const float*)d_in[7];
    float* out = (float*)d_out;

    float* ws   = (float*)d_ws;
    float* q1   = ws;                          // NV*DD
    float* h2   = q1 + (size_t)NV * DD;        // NV*DD
    float* p0   = h2 + (size_t)NV * DD;        // NV*FF
    float4* q04 = (float4*)(p0 + (size_t)NV * FF);  // NV (16B each, 16B-aligned)
    float* dinv = (float*)(q04 + NV);          // NV
    float* partials = dinv + NV;               // BB*PCH*64
    unsigned* parts = (unsigned*)(partials + BB * PCH * 64);  // KB*CAP
    int*   beg  = (int*)(parts + (size_t)KB * CAP);           // NV
    int*   end  = beg + NV;                    // NV
    int*   gcur = end + NV;                    // KB
    int*   flag = gcur + KB;                   // 1

    // --- Build bucketed, per-bucket-sorted edge structure ---
    setup_kernel<<<4, 256, 0, stream>>>(ei, flag, gcur);
    part_kernel<<<NBLKA, 256, 0, stream>>>(ei, flag, gcur, parts);
    bsort_kernel<<<KB, 256, 0, stream>>>(parts, gcur, beg, end, dinv);

    // --- p0 = dinv * temporal-mean(x) ---
    tmean_kernel<<<(NV * FF + 255) / 256, 256, 0, stream>>>(x, dinv, p0);

    // --- Layer 1 aggregation (3-dim gather) -> q04 = {q0, dinv} ---
    agg3_kernel<<<(NV + 255) / 256, 256, 0, stream>>>(beg, end, parts, p0, dinv, q04);

    // --- Fused layer-1 transform + layer-2 aggregation (16B/edge gather) ---
    aggf_kernel<<<NV * 64 / 256, 256, 0, stream>>>(beg, end, parts, q04, W1, b1, q1);

    // --- Layer-2 transform ---
    trans2_kernel<<<NV * DD / 256, 256, 0, stream>>>(q1, dinv, b2, W2, h2);

    // --- Pool + head (two-phase) ---
    pool_part_kernel<<<BB * PCH, 256, 0, stream>>>(h2, partials);
    pool_finish_kernel<<<BB, 64, 0, stream>>>(partials, Wh, bh, out);
}